// Round 8
// baseline (1012.213 us; speedup 1.0000x reference)
//
#include <hip/hip_runtime.h>
#include <math.h>

// Problem constants
#define TOK   4096    // B*N
#define EDIM  512
#define HEADS 8
#define DHEAD 64
#define GCOLS 32768   // H*D*D

typedef unsigned short u16;
typedef _Float16 f16;
typedef __attribute__((ext_vector_type(8))) f16 f16x8;      // 8 fp16 = 4 VGPRs (MFMA A/B frag)
typedef __attribute__((ext_vector_type(4))) f16 f16x4;
typedef __attribute__((ext_vector_type(4))) float f32x4;    // MFMA C/D frag
typedef __attribute__((ext_vector_type(4))) unsigned short u16x4;
typedef __attribute__((ext_vector_type(8))) unsigned short u16x8;

typedef const __attribute__((address_space(1))) void* gas_ptr;
typedef __attribute__((address_space(3))) void* las_ptr;

__device__ __forceinline__ void gll16(const void* g, void* lds) {
  // async global->LDS, 16B/lane: per-lane global addr, wave-uniform LDS base,
  // lane i lands at lds + i*16
  __builtin_amdgcn_global_load_lds((gas_ptr)g, (las_ptr)lds, 16, 0, 0);
}

__device__ __forceinline__ u16 f2h_bits(float f) {
  union { f16 h; u16 u; } v; v.h = (f16)f;   // RNE
  return v.u;
}

// Abramowitz-Stegun 7.1.26 erf: |abs err| <= 1.5e-7, ~15 VALU insts
__device__ __forceinline__ float fast_gelu(float x) {
  float s = x * 0.7071067811865475f;
  float ax = fabsf(s);
  float t = 1.0f / (1.0f + 0.3275911f * ax);
  float poly = t * (0.254829592f + t * (-0.284496736f + t * (1.421413741f +
               t * (-1.453152027f + t * 1.061405429f))));
  float e = __expf(-ax * ax);
  float r = 1.0f - poly * e;
  float erfv = copysignf(r, s);
  return 0.5f * x * (1.0f + erfv);
}

// ---------------------------------------------------------------- cast x -> fp16
__global__ void cast_f16_k(const float* __restrict__ in, u16* __restrict__ out, int n) {
  int i = (blockIdx.x * blockDim.x + threadIdx.x) * 4;
  if (i + 3 < n) {
    float4 f = *(const float4*)(in + i);
    u16x4 h;
    h.x = f2h_bits(f.x); h.y = f2h_bits(f.y);
    h.z = f2h_bits(f.z); h.w = f2h_bits(f.w);
    *(u16x4*)(out + i) = h;
  }
}

// -------------------- transpose W[K][N] -> Wt[N][K] fp16, 64x64 tile, u16x8 stores
__global__ void transpose_f16_k(const float* __restrict__ in, u16* __restrict__ out,
                                int K, int N) {
  __shared__ u16 tileT[64][72];   // [n_local][k_local], row 144B (16B-aligned)
  const int n0 = blockIdx.x * 64, k0 = blockIdx.y * 64;
  const int tid = threadIdx.x;    // 256
  const int kl = tid >> 4;        // 0..15
  const int nl4 = (tid & 15) * 4; // 0..60
  #pragma unroll
  for (int i = 0; i < 4; i++) {
    int k = kl + i * 16;
    float4 f = *(const float4*)(in + (size_t)(k0 + k) * N + n0 + nl4);
    tileT[nl4 + 0][k] = f2h_bits(f.x);
    tileT[nl4 + 1][k] = f2h_bits(f.y);
    tileT[nl4 + 2][k] = f2h_bits(f.z);
    tileT[nl4 + 3][k] = f2h_bits(f.w);
  }
  __syncthreads();
  const int nr = tid >> 3;         // 0..31
  const int ks = (tid & 7) * 8;    // 0..56
  #pragma unroll
  for (int p = 0; p < 2; p++) {
    int n = nr + p * 32;
    u16x8 v = *(const u16x8*)&tileT[n][ks];             // 16B LDS read
    *(u16x8*)(out + (size_t)(n0 + n) * K + k0 + ks) = v; // 16B global store
  }
}

// ---------------------------------------------------------------- QKV GEMM
// 128x128 tile, BK=64, 4 waves, fp16 MFMA, double-buffered LDS staging.
// q fp16 [B][H][N][D]; k fp16 [B][H][N][D]; v transposed fp16 [B][H][D][N].
__global__ __launch_bounds__(256, 2) void qkv_gemm_k(
    const u16* __restrict__ xf, const u16* __restrict__ Wqt,
    const u16* __restrict__ Wkt, const u16* __restrict__ Wvt,
    const float* __restrict__ bq, const float* __restrict__ bk, const float* __restrict__ bv,
    u16* __restrict__ qho, u16* __restrict__ ko, u16* __restrict__ vTo) {
  __shared__ __align__(16) u16 As[2][16 * 512];   // 2x16KB
  __shared__ __align__(16) u16 Bs[2][16 * 512];   // 2x16KB
  const int which = blockIdx.z;
  const u16* Wt = which == 0 ? Wqt : (which == 1 ? Wkt : Wvt);
  const float* bias = which == 0 ? bq : (which == 1 ? bk : bv);
  const int m0 = blockIdx.x * 128;
  const int n0 = blockIdx.y * 128;
  const int tid = threadIdx.x;
  const int w = tid >> 6, lane = tid & 63, l15 = lane & 15, quad = lane >> 4;
  const int mhalf = w >> 1, nhalf = w & 1;

  auto stage = [&](int s) {
    int kk = s * 64, buf = s & 1;
    #pragma unroll
    for (int i = 0; i < 8; i++) {
      int cb = w * 8 + i;
      if (cb < 16) {
        int ks = cb >> 3, mt = cb & 7;
        gll16(xf + (size_t)(m0 + mt * 16 + l15) * 512 + kk + ks * 32 + quad * 8,
              &As[buf][cb * 512]);
      } else {
        int bi = cb - 16, ks = bi >> 3, nt = bi & 7;
        gll16(Wt + (size_t)(n0 + nt * 16 + l15) * 512 + kk + ks * 32 + quad * 8,
              &Bs[buf][bi * 512]);
      }
    }
  };

  f32x4 acc[4][4];
  #pragma unroll
  for (int i = 0; i < 4; i++)
    #pragma unroll
    for (int j = 0; j < 4; j++) acc[i][j] = f32x4{0.f, 0.f, 0.f, 0.f};

  stage(0);
  __syncthreads();
  for (int s = 0; s < 8; s++) {
    if (s < 7) stage(s + 1);
    int buf = s & 1;
    #pragma unroll
    for (int ks = 0; ks < 2; ks++) {
      f16x8 a[4], b[4];
      #pragma unroll
      for (int mt = 0; mt < 4; mt++)
        a[mt] = *(const f16x8*)(&As[buf][(ks * 8 + mhalf * 4 + mt) * 512 + lane * 8]);
      #pragma unroll
      for (int nt = 0; nt < 4; nt++)
        b[nt] = *(const f16x8*)(&Bs[buf][(ks * 8 + nhalf * 4 + nt) * 512 + lane * 8]);
      #pragma unroll
      for (int mt = 0; mt < 4; mt++)
        #pragma unroll
        for (int nt = 0; nt < 4; nt++)
          acc[mt][nt] = __builtin_amdgcn_mfma_f32_16x16x32_f16(a[mt], b[nt], acc[mt][nt], 0, 0, 0);
    }
    __syncthreads();
  }
  #pragma unroll
  for (int nt = 0; nt < 4; nt++) {
    int col = n0 + (nhalf * 4 + nt) * 16 + l15;
    float bia = bias[col];
    int h = col >> 6, d = col & 63;
    #pragma unroll
    for (int mt = 0; mt < 4; mt++) {
      #pragma unroll
      for (int r = 0; r < 4; r++) {
        int t = m0 + (mhalf * 4 + mt) * 16 + quad * 4 + r;
        int b_ = t >> 10, n = t & 1023;
        float val = acc[mt][nt][r] + bia;
        size_t idx = (((size_t)(b_ * 8 + h) * 1024) + n) * 64 + d;
        if (which == 0)      qho[idx] = f2h_bits(val);
        else if (which == 1) ko[idx] = f2h_bits(val);
        else                 vTo[(((size_t)(b_ * 8 + h) * 64) + d) * 1024 + n] = f2h_bits(val);
      }
    }
  }
}

// ---------------------------------------------------------------- fused g-GEMM + q.g
// BARRIER-FREE K-loop. Block = 64 tokens x 1 head, 8 waves (512 thr).
// x-tile (64KB) + q (8KB) staged to LDS ONCE (one barrier); after that LDS is
// read-only (no vmcnt hazard on ds_read). Wg streams global->VGPR with register
// double-buffer (compiler emits precise vmcnt waits; waves slip freely).
// Wave (dp = w>>2, ntA = w&3) owns cols {d = 2*jc+dp} x {e-range ntA*16..+15};
// per pass processes 2 j-chunks (32 cols) sharing each A-read.
// qg partials split by dp -> qgp[dp] (stride TOK*EDIM), summed in attn_k.
__global__ __launch_bounds__(512, 4) void qg_fused_k(
    const u16* __restrict__ xf, const u16* __restrict__ Wgt,
    const float* __restrict__ bg, const u16* __restrict__ qh,
    float* __restrict__ qgp) {
  __shared__ __align__(16) u16 As[64 * 512];   // 64KB: frag (kb,mt) at (kb*4+mt)*512
  __shared__ __align__(16) u16 Qs[64 * 64];    // 8KB: q[t][d] fp16
  const int head = blockIdx.x & 7;             // XCD-pinned per head
  const int t0 = (blockIdx.x >> 3) * 64;
  const int tid = threadIdx.x;
  const int w = tid >> 6, lane = tid & 63, l15 = lane & 15, quad = lane >> 4;
  const int dp = w >> 2;      // 0..1  (d parity)
  const int ntA = w & 3;      // 0..3  (e-range /16)
  const int b_ = t0 >> 10, nseq0 = t0 & 1023;
  const u16* qbase = qh + (((size_t)(b_ * 8 + head) * 1024) + nseq0) * 64;

  // --- one-time LDS fill: x-tile (64 gll16) + q (8 gll16), then ONE barrier ---
  #pragma unroll
  for (int i = 0; i < 8; i++) {
    int cb = w * 8 + i;                 // 0..63 : kb = cb>>2, mt = cb&3
    int kb = cb >> 2, mt = cb & 3;
    gll16(xf + (size_t)(t0 + mt * 16 + l15) * 512 + kb * 32 + quad * 8,
          As + cb * 512);
  }
  gll16(qbase + (size_t)w * 512 + (size_t)lane * 8, Qs + (size_t)w * 512);
  __syncthreads();                      // only barrier in the kernel

  f32x4 qg[4];
  #pragma unroll
  for (int i = 0; i < 4; i++) qg[i] = f32x4{0.f, 0.f, 0.f, 0.f};

  for (int p = 0; p < 16; p++) {
    const int jc0 = p * 2;              // chunks jc0, jc0+1; d = 2*jc + dp
    // per-lane B row pointers (col includes l15)
    const u16* Bb0 = Wgt + (size_t)(head * 4096 + jc0 * 128 + dp * 64 + ntA * 16 + l15) * 512;
    const u16* Bb1 = Bb0 + (size_t)128 * 512;
    f32x4 zacc[4][2];
    #pragma unroll
    for (int i = 0; i < 4; i++) {
      zacc[i][0] = f32x4{0.f, 0.f, 0.f, 0.f};
      zacc[i][1] = f32x4{0.f, 0.f, 0.f, 0.f};
    }
    // register dbuf for B: [jcq][ks]
    u16x8 cur00 = *(const u16x8*)(Bb0 + quad * 8);
    u16x8 cur01 = *(const u16x8*)(Bb0 + 32 + quad * 8);
    u16x8 cur10 = *(const u16x8*)(Bb1 + quad * 8);
    u16x8 cur11 = *(const u16x8*)(Bb1 + 32 + quad * 8);
    #pragma unroll
    for (int kk = 0; kk < 8; kk++) {
      u16x8 nxt00, nxt01, nxt10, nxt11;
      if (kk < 7) {
        int o = (kk + 1) * 64 + quad * 8;
        nxt00 = *(const u16x8*)(Bb0 + o);
        nxt01 = *(const u16x8*)(Bb0 + 32 + o);
        nxt10 = *(const u16x8*)(Bb1 + o);
        nxt11 = *(const u16x8*)(Bb1 + 32 + o);
      }
      #pragma unroll
      for (int ks = 0; ks < 2; ks++) {
        f16x8 a[4];
        #pragma unroll
        for (int mt = 0; mt < 4; mt++)
          a[mt] = *(const f16x8*)(As + ((kk * 2 + ks) * 4 + mt) * 512 + lane * 8);
        f16x8 b0, b1;
        if (ks == 0) {
          b0 = *(const f16x8*)&cur00; b1 = *(const f16x8*)&cur10;
        } else {
          b0 = *(const f16x8*)&cur01; b1 = *(const f16x8*)&cur11;
        }
        #pragma unroll
        for (int mt = 0; mt < 4; mt++) {
          zacc[mt][0] = __builtin_amdgcn_mfma_f32_16x16x32_f16(a[mt], b0, zacc[mt][0], 0, 0, 0);
          zacc[mt][1] = __builtin_amdgcn_mfma_f32_16x16x32_f16(a[mt], b1, zacc[mt][1], 0, 0, 0);
        }
      }
      cur00 = nxt00; cur01 = nxt01; cur10 = nxt10; cur11 = nxt11;
    }
    // epilogue: bias + fast gelu + contract with q from LDS
    const int cb0 = head * 4096 + jc0 * 128 + dp * 64 + ntA * 16 + l15;
    float bg0 = bg[cb0];
    float bg1 = bg[cb0 + 128];
    const int d0 = 2 * jc0 + dp, d1 = 2 * (jc0 + 1) + dp;
    const f16* Qf = (const f16*)Qs;
    #pragma unroll
    for (int mt = 0; mt < 4; mt++) {
      #pragma unroll
      for (int r = 0; r < 4; r++) {
        int row = mt * 16 + quad * 4 + r;
        float q0 = (float)Qf[row * 64 + d0];
        float q1 = (float)Qf[row * 64 + d1];
        qg[mt][r] += q0 * fast_gelu(zacc[mt][0][r] + bg0) +
                     q1 * fast_gelu(zacc[mt][1][r] + bg1);
      }
    }
  }
  float* qout = qgp + (size_t)dp * TOK * EDIM;   // partial by d-parity
  const int eb = ntA * 16;
  #pragma unroll
  for (int mt = 0; mt < 4; mt++) {
    #pragma unroll
    for (int r = 0; r < 4; r++) {
      int t = t0 + mt * 16 + quad * 4 + r;
      int bb = t >> 10, n = t & 1023;
      qout[(((size_t)(bb * 8 + head) * 1024) + n) * 64 + eb + l15] = qg[mt][r];
    }
  }
}

// ---------------------------------------------------------------- flash attention
// Block = (b,h,qtile64), 4 waves x 16 q-rows. qg = partial0+partial1 (fp32->fp16),
// S = qg@k^T fp16 MFMA, online softmax, P->LDS (C->A layout turn), O += P@V.
__global__ __launch_bounds__(256, 2) void attn_k(
    const float* __restrict__ qgp, const u16* __restrict__ kb,
    const u16* __restrict__ vTb, float* __restrict__ out) {
  __shared__ __align__(16) u16 Ks[8 * 512];
  __shared__ __align__(16) u16 Vs[8 * 512];
  __shared__ __align__(16) f16 Ps[4][16 * 72];    // per-wave P, row stride 72
  const int idx = blockIdx.x;
  const int bh = idx & 31;   // b*8+h -> XCD = bh%8
  const int qt = idx >> 5;
  const int b_ = bh >> 3, h = bh & 7;
  const int tid = threadIdx.x;
  const int w = tid >> 6, lane = tid & 63, l15 = lane & 15, quad = lane >> 4;

  const float* qg0 = qgp + (size_t)bh * 1024 * 64;
  const float* qg1 = qg0 + (size_t)TOK * EDIM;   // partial stride = 2M elems
  const u16* kB  = kb  + (size_t)bh * 1024 * 64;
  const u16* vB  = vTb + (size_t)bh * 64 * 1024;

  f16x8 aq[2];
  #pragma unroll
  for (int ks = 0; ks < 2; ks++) {
    size_t off = (size_t)(qt * 64 + w * 16 + l15) * 64 + ks * 32 + quad * 8;
    f16x8 v;
    #pragma unroll
    for (int e = 0; e < 8; e++)
      v[e] = (f16)(qg0[off + e] + qg1[off + e]);
    aq[ks] = v;
  }

  f32x4 o[4];
  #pragma unroll
  for (int i = 0; i < 4; i++) o[i] = f32x4{0.f, 0.f, 0.f, 0.f};
  float m_old[4], l_old[4];
  #pragma unroll
  for (int r = 0; r < 4; r++) { m_old[r] = -1e30f; l_old[r] = 0.f; }

  for (int kt = 0; kt < 16; kt++) {
    #pragma unroll
    for (int i = 0; i < 2; i++) {
      int cb = w * 2 + i;
      int ks = cb >> 2, nt = cb & 3;
      gll16(kB + (size_t)(kt * 64 + nt * 16 + l15) * 64 + ks * 32 + quad * 8, Ks + cb * 512);
      gll16(vB + (size_t)(nt * 16 + l15) * 1024 + kt * 64 + ks * 32 + quad * 8, Vs + cb * 512);
    }
    __syncthreads();
    f32x4 s[4];
    #pragma unroll
    for (int nt = 0; nt < 4; nt++) s[nt] = f32x4{0.f, 0.f, 0.f, 0.f};
    #pragma unroll
    for (int ks = 0; ks < 2; ks++)
      #pragma unroll
      for (int nt = 0; nt < 4; nt++) {
        f16x8 kf = *(const f16x8*)(Ks + (ks * 4 + nt) * 512 + lane * 8);
        s[nt] = __builtin_amdgcn_mfma_f32_16x16x32_f16(aq[ks], kf, s[nt], 0, 0, 0);
      }
    float rmax[4];
    #pragma unroll
    for (int r = 0; r < 4; r++)
      rmax[r] = fmaxf(fmaxf(s[0][r], s[1][r]), fmaxf(s[2][r], s[3][r]));
    #pragma unroll
    for (int off = 1; off < 16; off <<= 1)
      #pragma unroll
      for (int r = 0; r < 4; r++)
        rmax[r] = fmaxf(rmax[r], __shfl_xor(rmax[r], off));
    float alpha[4], rsum[4];
    #pragma unroll
    for (int r = 0; r < 4; r++) {
      float mn = fmaxf(m_old[r], rmax[r]);
      alpha[r] = __expf(m_old[r] - mn);
      m_old[r] = mn;
      rsum[r] = 0.f;
    }
    #pragma unroll
    for (int nt = 0; nt < 4; nt++)
      #pragma unroll
      for (int r = 0; r < 4; r++) {
        float p = __expf(s[nt][r] - m_old[r]);
        rsum[r] += p;
        Ps[w][(quad * 4 + r) * 72 + nt * 16 + l15] = (f16)p;
      }
    #pragma unroll
    for (int off = 1; off < 16; off <<= 1)
      #pragma unroll
      for (int r = 0; r < 4; r++)
        rsum[r] += __shfl_xor(rsum[r], off);
    #pragma unroll
    for (int r = 0; r < 4; r++) l_old[r] = l_old[r] * alpha[r] + rsum[r];
    #pragma unroll
    for (int nt = 0; nt < 4; nt++)
      #pragma unroll
      for (int r = 0; r < 4; r++) o[nt][r] *= alpha[r];
    #pragma unroll
    for (int ks = 0; ks < 2; ks++) {
      f16x8 pa = *(const f16x8*)(&Ps[w][l15 * 72 + ks * 32 + quad * 8]);
      #pragma unroll
      for (int nt = 0; nt < 4; nt++) {
        f16x8 vf = *(const f16x8*)(Vs + (ks * 4 + nt) * 512 + lane * 8);
        o[nt] = __builtin_amdgcn_mfma_f32_16x16x32_f16(pa, vf, o[nt], 0, 0, 0);
      }
    }
    __syncthreads();
  }
  #pragma unroll
  for (int r = 0; r < 4; r++) {
    float inv = 1.f / l_old[r];
    int n = qt * 64 + w * 16 + quad * 4 + r;
    #pragma unroll
    for (int nt = 0; nt < 4; nt++)
      out[((size_t)(b_ * 1024 + n)) * 512 + h * 64 + nt * 16 + l15] = o[nt][r] * inv;
  }
}

// ----------------------------------------------------------------------- host
extern "C" void kernel_launch(void* const* d_in, const int* in_sizes, int n_in,
                              void* d_out, int out_size, void* d_ws, size_t ws_size,
                              hipStream_t stream) {
  const float* x  = (const float*)d_in[0];
  const float* Wq = (const float*)d_in[1];
  const float* bq = (const float*)d_in[2];
  const float* Wk = (const float*)d_in[3];
  const float* bk = (const float*)d_in[4];
  const float* Wv = (const float*)d_in[5];
  const float* bv = (const float*)d_in[6];
  const float* Wg = (const float*)d_in[7];
  const float* bg = (const float*)d_in[8];
  float* out = (float*)d_out;

  const size_t NX = (size_t)TOK * EDIM;        // 2M elems
  const size_t NWG = (size_t)GCOLS * EDIM;     // 16.8M elems
  const size_t NW = (size_t)EDIM * EDIM;       // 256K elems

  char* p = (char*)d_ws;
  u16* xf  = (u16*)p; p += NX * 2;             // x fp16
  u16* Wgt = (u16*)p; p += NWG * 2;            // Wg^T fp16 (33.5 MB)
  u16* Wqt = (u16*)p; p += NW * 2;
  u16* Wkt = (u16*)p; p += NW * 2;
  u16* Wvt = (u16*)p; p += NW * 2;
  u16* qh  = (u16*)p; p += NX * 2;             // q fp16 [B][H][N][D]
  u16* kf  = (u16*)p; p += NX * 2;             // k fp16
  u16* vT  = (u16*)p; p += NX * 2;             // v^T fp16
  float* qgp = (float*)p; p += NX * 4 * 2;     // qg fp32 partials [2][B][H][N][D] (by d-parity)

  hipLaunchKernelGGL(cast_f16_k, dim3(NX / 1024), dim3(256), 0, stream,
                     x, xf, (int)NX);
  hipLaunchKernelGGL(transpose_f16_k, dim3(EDIM / 64, EDIM / 64), dim3(256), 0, stream,
                     Wq, Wqt, EDIM, EDIM);
  hipLaunchKernelGGL(transpose_f16_k, dim3(EDIM / 64, EDIM / 64), dim3(256), 0, stream,
                     Wk, Wkt, EDIM, EDIM);
  hipLaunchKernelGGL(transpose_f16_k, dim3(EDIM / 64, EDIM / 64), dim3(256), 0, stream,
                     Wv, Wvt, EDIM, EDIM);
  hipLaunchKernelGGL(transpose_f16_k, dim3(GCOLS / 64, EDIM / 64), dim3(256), 0, stream,
                     Wg, Wgt, EDIM, GCOLS);
  hipLaunchKernelGGL(qkv_gemm_k, dim3(TOK / 128, EDIM / 128, 3), dim3(256), 0, stream,
                     xf, Wqt, Wkt, Wvt, bq, bk, bv, qh, kf, vT);
  hipLaunchKernelGGL(qg_fused_k, dim3((TOK / 64) * 8), dim3(512), 0, stream,
                     xf, Wgt, bg, qh, qgp);
  hipLaunchKernelGGL(attn_k, dim3(512), dim3(256), 0, stream,
                     qgp, kf, vT, out);
}

// Round 9
// 599.798 us; speedup vs baseline: 1.6876x; 1.6876x over previous
//
#include <hip/hip_runtime.h>
#include <math.h>

// Problem constants
#define TOK   4096    // B*N
#define EDIM  512
#define HEADS 8
#define DHEAD 64
#define GCOLS 32768   // H*D*D

typedef unsigned short u16;
typedef _Float16 f16;
typedef __attribute__((ext_vector_type(8))) f16 f16x8;      // 8 fp16 = 4 VGPRs (MFMA A/B frag)
typedef __attribute__((ext_vector_type(4))) float f32x4;    // MFMA C/D frag
typedef __attribute__((ext_vector_type(4))) unsigned short u16x4;
typedef __attribute__((ext_vector_type(8))) unsigned short u16x8;

typedef const __attribute__((address_space(1))) void* gas_ptr;
typedef __attribute__((address_space(3))) void* las_ptr;

__device__ __forceinline__ void gll16(const void* g, void* lds) {
  // async global->LDS, 16B/lane: per-lane global addr, wave-uniform LDS base,
  // lane i lands at lds + i*16
  __builtin_amdgcn_global_load_lds((gas_ptr)g, (las_ptr)lds, 16, 0, 0);
}

__device__ __forceinline__ u16 f2h_bits(float f) {
  union { f16 h; u16 u; } v; v.h = (f16)f;   // RNE
  return v.u;
}
__device__ __forceinline__ float h2f(u16 b) {
  union { u16 u; f16 h; } v; v.u = b;
  return (float)v.h;
}

// Abramowitz-Stegun 7.1.26 erf: |abs err| <= 1.5e-7, ~15 VALU insts
__device__ __forceinline__ float fast_gelu(float x) {
  float s = x * 0.7071067811865475f;
  float ax = fabsf(s);
  float t = 1.0f / (1.0f + 0.3275911f * ax);
  float poly = t * (0.254829592f + t * (-0.284496736f + t * (1.421413741f +
               t * (-1.453152027f + t * 1.061405429f))));
  float e = __expf(-ax * ax);
  float r = 1.0f - poly * e;
  float erfv = copysignf(r, s);
  return 0.5f * x * (1.0f + erfv);
}

// ---------------------------------------------------------------- cast x -> fp16
__global__ void cast_f16_k(const float* __restrict__ in, u16* __restrict__ out, int n) {
  int i = (blockIdx.x * blockDim.x + threadIdx.x) * 4;
  if (i + 3 < n) {
    float4 f = *(const float4*)(in + i);
    u16x4 h;
    h.x = f2h_bits(f.x); h.y = f2h_bits(f.y);
    h.z = f2h_bits(f.z); h.w = f2h_bits(f.w);
    *(u16x4*)(out + i) = h;
  }
}

// -------------------- transpose W[K][N] -> Wt[N][K] fp16, 64x64 tile, u16x8 stores
__global__ void transpose_f16_k(const float* __restrict__ in, u16* __restrict__ out,
                                int K, int N) {
  __shared__ u16 tileT[64][72];   // [n_local][k_local], row 144B (16B-aligned)
  const int n0 = blockIdx.x * 64, k0 = blockIdx.y * 64;
  const int tid = threadIdx.x;    // 256
  const int kl = tid >> 4;        // 0..15
  const int nl4 = (tid & 15) * 4; // 0..60
  #pragma unroll
  for (int i = 0; i < 4; i++) {
    int k = kl + i * 16;
    float4 f = *(const float4*)(in + (size_t)(k0 + k) * N + n0 + nl4);
    tileT[nl4 + 0][k] = f2h_bits(f.x);
    tileT[nl4 + 1][k] = f2h_bits(f.y);
    tileT[nl4 + 2][k] = f2h_bits(f.z);
    tileT[nl4 + 3][k] = f2h_bits(f.w);
  }
  __syncthreads();
  const int nr = tid >> 3;         // 0..31
  const int ks = (tid & 7) * 8;    // 0..56
  #pragma unroll
  for (int p = 0; p < 2; p++) {
    int n = nr + p * 32;
    u16x8 v = *(const u16x8*)&tileT[n][ks];             // 16B LDS read
    *(u16x8*)(out + (size_t)(n0 + n) * K + k0 + ks) = v; // 16B global store
  }
}

// ---------------------------------------------------------------- QKV GEMM
// 128x128 tile, BK=64, 4 waves, fp16 MFMA, double-buffered LDS staging.
// q fp16 [B][H][N][D]; k fp16 [B][H][N][D]; v transposed fp16 [B][H][D][N].
__global__ __launch_bounds__(256, 2) void qkv_gemm_k(
    const u16* __restrict__ xf, const u16* __restrict__ Wqt,
    const u16* __restrict__ Wkt, const u16* __restrict__ Wvt,
    const float* __restrict__ bq, const float* __restrict__ bk, const float* __restrict__ bv,
    u16* __restrict__ qho, u16* __restrict__ ko, u16* __restrict__ vTo) {
  __shared__ __align__(16) u16 As[2][16 * 512];   // 2x16KB
  __shared__ __align__(16) u16 Bs[2][16 * 512];   // 2x16KB
  const int which = blockIdx.z;
  const u16* Wt = which == 0 ? Wqt : (which == 1 ? Wkt : Wvt);
  const float* bias = which == 0 ? bq : (which == 1 ? bk : bv);
  const int m0 = blockIdx.x * 128;
  const int n0 = blockIdx.y * 128;
  const int tid = threadIdx.x;
  const int w = tid >> 6, lane = tid & 63, l15 = lane & 15, quad = lane >> 4;
  const int mhalf = w >> 1, nhalf = w & 1;

  auto stage = [&](int s) {
    int kk = s * 64, buf = s & 1;
    #pragma unroll
    for (int i = 0; i < 8; i++) {
      int cb = w * 8 + i;
      if (cb < 16) {
        int ks = cb >> 3, mt = cb & 7;
        gll16(xf + (size_t)(m0 + mt * 16 + l15) * 512 + kk + ks * 32 + quad * 8,
              &As[buf][cb * 512]);
      } else {
        int bi = cb - 16, ks = bi >> 3, nt = bi & 7;
        gll16(Wt + (size_t)(n0 + nt * 16 + l15) * 512 + kk + ks * 32 + quad * 8,
              &Bs[buf][bi * 512]);
      }
    }
  };

  f32x4 acc[4][4];
  #pragma unroll
  for (int i = 0; i < 4; i++)
    #pragma unroll
    for (int j = 0; j < 4; j++) acc[i][j] = f32x4{0.f, 0.f, 0.f, 0.f};

  stage(0);
  __syncthreads();
  for (int s = 0; s < 8; s++) {
    if (s < 7) stage(s + 1);
    int buf = s & 1;
    #pragma unroll
    for (int ks = 0; ks < 2; ks++) {
      f16x8 a[4], b[4];
      #pragma unroll
      for (int mt = 0; mt < 4; mt++)
        a[mt] = *(const f16x8*)(&As[buf][(ks * 8 + mhalf * 4 + mt) * 512 + lane * 8]);
      #pragma unroll
      for (int nt = 0; nt < 4; nt++)
        b[nt] = *(const f16x8*)(&Bs[buf][(ks * 8 + nhalf * 4 + nt) * 512 + lane * 8]);
      #pragma unroll
      for (int mt = 0; mt < 4; mt++)
        #pragma unroll
        for (int nt = 0; nt < 4; nt++)
          acc[mt][nt] = __builtin_amdgcn_mfma_f32_16x16x32_f16(a[mt], b[nt], acc[mt][nt], 0, 0, 0);
    }
    __syncthreads();
  }
  #pragma unroll
  for (int nt = 0; nt < 4; nt++) {
    int col = n0 + (nhalf * 4 + nt) * 16 + l15;
    float bia = bias[col];
    int h = col >> 6, d = col & 63;
    #pragma unroll
    for (int mt = 0; mt < 4; mt++) {
      #pragma unroll
      for (int r = 0; r < 4; r++) {
        int t = m0 + (mhalf * 4 + mt) * 16 + quad * 4 + r;
        int b_ = t >> 10, n = t & 1023;
        float val = acc[mt][nt][r] + bia;
        size_t idx = (((size_t)(b_ * 8 + h) * 1024) + n) * 64 + d;
        if (which == 0)      qho[idx] = f2h_bits(val);
        else if (which == 1) ko[idx] = f2h_bits(val);
        else                 vTo[(((size_t)(b_ * 8 + h) * 64) + d) * 1024 + n] = f2h_bits(val);
      }
    }
  }
}

// ---------------------------------------------------------------- fused g-GEMM + q.g
// R9: 3-blocks/CU variant. Block = 256 thr (4 waves) = 128 tok x head x j-quarter
// (8 chunks). Per stage: one 128-col chunk slice, As 16KB + Bs 16KB = 32KB LDS
// -> 3 blocks/CU (96KB), 12 waves/CU. Wave = (mhalf, eh): 64 tok x 32 e,
// covers BOTH d-parities in-wave -> qg private 32 regs, single partial per jq.
// q pairs read from global per chunk (L2-hot, no Qs). Grid jq-slowest so
// co-resident blocks on an XCD share a 1MB Wg quarter-slab (L2-resident).
// qg partial stride = TOK*EDIM; attn_k sums 4.
__global__ __launch_bounds__(256, 3) void qg_fused_k(
    const u16* __restrict__ xf, const u16* __restrict__ Wgt,
    const float* __restrict__ bg, const u16* __restrict__ qh,
    float* __restrict__ qgp) {
  __shared__ __align__(16) u16 As[16 * 512];   // 16KB: 128 tok x 64 K
  __shared__ __align__(16) u16 Bs[16 * 512];   // 16KB: 128 cols x 64 K
  const int bx = blockIdx.x;
  const int head = bx & 7;              // XCD-pinned per head
  const int t0 = ((bx >> 3) & 31) * 128;
  const int jq = bx >> 8;               // 0..3, slowest -> L2 locality
  const int tid = threadIdx.x;
  const int w = tid >> 6, lane = tid & 63, l15 = lane & 15, quad = lane >> 4;
  const int mhalf = w >> 1;   // token half
  const int eh = w & 1;       // e half (32-wide)
  const int b_ = t0 >> 10, nseq0 = t0 & 1023;
  const u16* qbase = qh + (((size_t)(b_ * 8 + head) * 1024) + nseq0) * 64;

  f32x4 qg[4][2];   // [mt][ef]: 64 tok x 32 e, both d summed in-wave
  #pragma unroll
  for (int mt = 0; mt < 4; mt++) {
    qg[mt][0] = f32x4{0.f, 0.f, 0.f, 0.f};
    qg[mt][1] = f32x4{0.f, 0.f, 0.f, 0.f};
  }

  for (int jc = 0; jc < 8; jc++) {
    const int j = jq * 8 + jc;
    const int c0 = head * 4096 + j * 128;
    // preload q pairs q[t][2j], q[t][2j+1] (dword each) - consumed 8 stages later
    unsigned qpair[4][4];
    #pragma unroll
    for (int mt = 0; mt < 4; mt++)
      #pragma unroll
      for (int r = 0; r < 4; r++) {
        int tl = mhalf * 64 + mt * 16 + quad * 4 + r;
        qpair[mt][r] = *(const unsigned*)(qbase + (size_t)tl * 64 + 2 * j);
      }
    // preload bias for this chunk's 4 (dd,ef) columns
    float bgv[4];
    #pragma unroll
    for (int z = 0; z < 4; z++) {
      int nt = (z >> 1) * 4 + eh * 2 + (z & 1);
      bgv[z] = bg[c0 + nt * 16 + l15];
    }

    f32x4 zacc[4][4];   // [mt][z], z = dd*2 + ef
    #pragma unroll
    for (int mt = 0; mt < 4; mt++)
      #pragma unroll
      for (int z = 0; z < 4; z++) zacc[mt][z] = f32x4{0.f, 0.f, 0.f, 0.f};

    for (int kk = 0; kk < 8; kk++) {
      #pragma unroll
      for (int i = 0; i < 8; i++) {
        int cb = w * 8 + i;
        if (cb < 16) {
          int ks = cb >> 3, mt = cb & 7;
          gll16(xf + (size_t)(t0 + mt * 16 + l15) * 512 + kk * 64 + ks * 32 + quad * 8,
                As + cb * 512);
        } else {
          int bi = cb - 16, ks = bi >> 3, nt = bi & 7;
          gll16(Wgt + (size_t)(c0 + nt * 16 + l15) * 512 + kk * 64 + ks * 32 + quad * 8,
                Bs + bi * 512);
        }
      }
      __syncthreads();
      #pragma unroll
      for (int ks = 0; ks < 2; ks++) {
        f16x8 a[4];
        #pragma unroll
        for (int mt = 0; mt < 4; mt++)
          a[mt] = *(const f16x8*)(As + (ks * 8 + mhalf * 4 + mt) * 512 + lane * 8);
        #pragma unroll
        for (int z = 0; z < 4; z++) {
          int nt = (z >> 1) * 4 + eh * 2 + (z & 1);
          f16x8 b = *(const f16x8*)(Bs + (ks * 8 + nt) * 512 + lane * 8);
          #pragma unroll
          for (int mt = 0; mt < 4; mt++)
            zacc[mt][z] = __builtin_amdgcn_mfma_f32_16x16x32_f16(a[mt], b, zacc[mt][z], 0, 0, 0);
        }
      }
      __syncthreads();
    }
    // epilogue: bias + fast gelu + q-contraction (both d in-wave)
    #pragma unroll
    for (int mt = 0; mt < 4; mt++) {
      #pragma unroll
      for (int r = 0; r < 4; r++) {
        float q0 = h2f((u16)(qpair[mt][r] & 0xffffu));
        float q1 = h2f((u16)(qpair[mt][r] >> 16));
        qg[mt][0][r] += q0 * fast_gelu(zacc[mt][0][r] + bgv[0]) +
                        q1 * fast_gelu(zacc[mt][2][r] + bgv[2]);
        qg[mt][1][r] += q0 * fast_gelu(zacc[mt][1][r] + bgv[1]) +
                        q1 * fast_gelu(zacc[mt][3][r] + bgv[3]);
      }
    }
  }
  float* qout = qgp + (size_t)jq * TOK * EDIM;   // partial per j-quarter
  #pragma unroll
  for (int mt = 0; mt < 4; mt++) {
    #pragma unroll
    for (int ef = 0; ef < 2; ef++) {
      #pragma unroll
      for (int r = 0; r < 4; r++) {
        int t = t0 + mhalf * 64 + mt * 16 + quad * 4 + r;
        int bb = t >> 10, n = t & 1023;
        int e = eh * 32 + ef * 16 + l15;
        qout[(((size_t)(bb * 8 + head) * 1024) + n) * 64 + e] = qg[mt][ef][r];
      }
    }
  }
}

// ---------------------------------------------------------------- flash attention
// Block = (b,h,qtile64), 4 waves x 16 q-rows. qg = sum of 4 jq-partials
// (fp32->fp16), S = qg@k^T fp16 MFMA, online softmax, P->LDS, O += P@V.
__global__ __launch_bounds__(256, 2) void attn_k(
    const float* __restrict__ qgp, const u16* __restrict__ kb,
    const u16* __restrict__ vTb, float* __restrict__ out) {
  __shared__ __align__(16) u16 Ks[8 * 512];
  __shared__ __align__(16) u16 Vs[8 * 512];
  __shared__ __align__(16) f16 Ps[4][16 * 72];    // per-wave P, row stride 72
  const int idx = blockIdx.x;
  const int bh = idx & 31;   // b*8+h -> XCD = bh%8
  const int qt = idx >> 5;
  const int b_ = bh >> 3, h = bh & 7;
  const int tid = threadIdx.x;
  const int w = tid >> 6, lane = tid & 63, l15 = lane & 15, quad = lane >> 4;

  const size_t S = (size_t)TOK * EDIM;           // partial stride
  const float* qgB = qgp + (size_t)bh * 1024 * 64;
  const u16* kB  = kb  + (size_t)bh * 1024 * 64;
  const u16* vB  = vTb + (size_t)bh * 64 * 1024;

  f16x8 aq[2];
  #pragma unroll
  for (int ks = 0; ks < 2; ks++) {
    size_t off = (size_t)(qt * 64 + w * 16 + l15) * 64 + ks * 32 + quad * 8;
    f16x8 v;
    #pragma unroll
    for (int e = 0; e < 8; e++)
      v[e] = (f16)(qgB[off + e] + qgB[S + off + e] + qgB[2 * S + off + e] + qgB[3 * S + off + e]);
    aq[ks] = v;
  }

  f32x4 o[4];
  #pragma unroll
  for (int i = 0; i < 4; i++) o[i] = f32x4{0.f, 0.f, 0.f, 0.f};
  float m_old[4], l_old[4];
  #pragma unroll
  for (int r = 0; r < 4; r++) { m_old[r] = -1e30f; l_old[r] = 0.f; }

  for (int kt = 0; kt < 16; kt++) {
    #pragma unroll
    for (int i = 0; i < 2; i++) {
      int cb = w * 2 + i;
      int ks = cb >> 2, nt = cb & 3;
      gll16(kB + (size_t)(kt * 64 + nt * 16 + l15) * 64 + ks * 32 + quad * 8, Ks + cb * 512);
      gll16(vB + (size_t)(nt * 16 + l15) * 1024 + kt * 64 + ks * 32 + quad * 8, Vs + cb * 512);
    }
    __syncthreads();
    f32x4 s[4];
    #pragma unroll
    for (int nt = 0; nt < 4; nt++) s[nt] = f32x4{0.f, 0.f, 0.f, 0.f};
    #pragma unroll
    for (int ks = 0; ks < 2; ks++)
      #pragma unroll
      for (int nt = 0; nt < 4; nt++) {
        f16x8 kf = *(const f16x8*)(Ks + (ks * 4 + nt) * 512 + lane * 8);
        s[nt] = __builtin_amdgcn_mfma_f32_16x16x32_f16(aq[ks], kf, s[nt], 0, 0, 0);
      }
    float rmax[4];
    #pragma unroll
    for (int r = 0; r < 4; r++)
      rmax[r] = fmaxf(fmaxf(s[0][r], s[1][r]), fmaxf(s[2][r], s[3][r]));
    #pragma unroll
    for (int off = 1; off < 16; off <<= 1)
      #pragma unroll
      for (int r = 0; r < 4; r++)
        rmax[r] = fmaxf(rmax[r], __shfl_xor(rmax[r], off));
    float alpha[4], rsum[4];
    #pragma unroll
    for (int r = 0; r < 4; r++) {
      float mn = fmaxf(m_old[r], rmax[r]);
      alpha[r] = __expf(m_old[r] - mn);
      m_old[r] = mn;
      rsum[r] = 0.f;
    }
    #pragma unroll
    for (int nt = 0; nt < 4; nt++)
      #pragma unroll
      for (int r = 0; r < 4; r++) {
        float p = __expf(s[nt][r] - m_old[r]);
        rsum[r] += p;
        Ps[w][(quad * 4 + r) * 72 + nt * 16 + l15] = (f16)p;
      }
    #pragma unroll
    for (int off = 1; off < 16; off <<= 1)
      #pragma unroll
      for (int r = 0; r < 4; r++)
        rsum[r] += __shfl_xor(rsum[r], off);
    #pragma unroll
    for (int r = 0; r < 4; r++) l_old[r] = l_old[r] * alpha[r] + rsum[r];
    #pragma unroll
    for (int nt = 0; nt < 4; nt++)
      #pragma unroll
      for (int r = 0; r < 4; r++) o[nt][r] *= alpha[r];
    #pragma unroll
    for (int ks = 0; ks < 2; ks++) {
      f16x8 pa = *(const f16x8*)(&Ps[w][l15 * 72 + ks * 32 + quad * 8]);
      #pragma unroll
      for (int nt = 0; nt < 4; nt++) {
        f16x8 vf = *(const f16x8*)(Vs + (ks * 4 + nt) * 512 + lane * 8);
        o[nt] = __builtin_amdgcn_mfma_f32_16x16x32_f16(pa, vf, o[nt], 0, 0, 0);
      }
    }
    __syncthreads();
  }
  #pragma unroll
  for (int r = 0; r < 4; r++) {
    float inv = 1.f / l_old[r];
    int n = qt * 64 + w * 16 + quad * 4 + r;
    #pragma unroll
    for (int nt = 0; nt < 4; nt++)
      out[((size_t)(b_ * 1024 + n)) * 512 + h * 64 + nt * 16 + l15] = o[nt][r] * inv;
  }
}

// ----------------------------------------------------------------------- host
extern "C" void kernel_launch(void* const* d_in, const int* in_sizes, int n_in,
                              void* d_out, int out_size, void* d_ws, size_t ws_size,
                              hipStream_t stream) {
  const float* x  = (const float*)d_in[0];
  const float* Wq = (const float*)d_in[1];
  const float* bq = (const float*)d_in[2];
  const float* Wk = (const float*)d_in[3];
  const float* bk = (const float*)d_in[4];
  const float* Wv = (const float*)d_in[5];
  const float* bv = (const float*)d_in[6];
  const float* Wg = (const float*)d_in[7];
  const float* bg = (const float*)d_in[8];
  float* out = (float*)d_out;

  const size_t NX = (size_t)TOK * EDIM;        // 2M elems
  const size_t NWG = (size_t)GCOLS * EDIM;     // 16.8M elems
  const size_t NW = (size_t)EDIM * EDIM;       // 256K elems

  char* p = (char*)d_ws;
  u16* xf  = (u16*)p; p += NX * 2;             // x fp16
  u16* Wgt = (u16*)p; p += NWG * 2;            // Wg^T fp16 (33.5 MB)
  u16* Wqt = (u16*)p; p += NW * 2;
  u16* Wkt = (u16*)p; p += NW * 2;
  u16* Wvt = (u16*)p; p += NW * 2;
  u16* qh  = (u16*)p; p += NX * 2;             // q fp16 [B][H][N][D]
  u16* kf  = (u16*)p; p += NX * 2;             // k fp16
  u16* vT  = (u16*)p; p += NX * 2;             // v^T fp16
  float* qgp = (float*)p; p += NX * 4 * 4;     // qg fp32 partials [4 jq][B][H][N][D]

  hipLaunchKernelGGL(cast_f16_k, dim3(NX / 1024), dim3(256), 0, stream,
                     x, xf, (int)NX);
  hipLaunchKernelGGL(transpose_f16_k, dim3(EDIM / 64, EDIM / 64), dim3(256), 0, stream,
                     Wq, Wqt, EDIM, EDIM);
  hipLaunchKernelGGL(transpose_f16_k, dim3(EDIM / 64, EDIM / 64), dim3(256), 0, stream,
                     Wk, Wkt, EDIM, EDIM);
  hipLaunchKernelGGL(transpose_f16_k, dim3(EDIM / 64, EDIM / 64), dim3(256), 0, stream,
                     Wv, Wvt, EDIM, EDIM);
  hipLaunchKernelGGL(transpose_f16_k, dim3(GCOLS / 64, EDIM / 64), dim3(256), 0, stream,
                     Wg, Wgt, EDIM, GCOLS);
  hipLaunchKernelGGL(qkv_gemm_k, dim3(TOK / 128, EDIM / 128, 3), dim3(256), 0, stream,
                     xf, Wqt, Wkt, Wvt, bq, bk, bv, qh, kf, vT);
  hipLaunchKernelGGL(qg_fused_k, dim3(1024), dim3(256), 0, stream,
                     xf, Wgt, bg, qh, qgp);
  hipLaunchKernelGGL(attn_k, dim3(512), dim3(256), 0, stream,
                     qgp, kf, vT, out);
}

// Round 10
// 566.686 us; speedup vs baseline: 1.7862x; 1.0584x over previous
//
#include <hip/hip_runtime.h>
#include <math.h>

// Problem constants
#define TOK   4096    // B*N
#define EDIM  512
#define HEADS 8
#define DHEAD 64
#define GCOLS 32768   // H*D*D

typedef unsigned short u16;
typedef _Float16 f16;
typedef __attribute__((ext_vector_type(8))) f16 f16x8;      // 8 fp16 = 4 VGPRs (MFMA A/B frag)
typedef __attribute__((ext_vector_type(4))) float f32x4;    // MFMA C/D frag
typedef __attribute__((ext_vector_type(4))) unsigned short u16x4;
typedef __attribute__((ext_vector_type(8))) unsigned short u16x8;

typedef const __attribute__((address_space(1))) void* gas_ptr;
typedef __attribute__((address_space(3))) void* las_ptr;

__device__ __forceinline__ void gll16(const void* g, void* lds) {
  // async global->LDS, 16B/lane: per-lane global addr, wave-uniform LDS base,
  // lane i lands at lds + i*16
  __builtin_amdgcn_global_load_lds((gas_ptr)g, (las_ptr)lds, 16, 0, 0);
}

__device__ __forceinline__ u16 f2h_bits(float f) {
  union { f16 h; u16 u; } v; v.h = (f16)f;   // RNE
  return v.u;
}
__device__ __forceinline__ float h2f(u16 b) {
  union { u16 u; f16 h; } v; v.u = b;
  return (float)v.h;
}

// Abramowitz-Stegun 7.1.26 erf: |abs err| <= 1.5e-7, ~15 VALU insts
__device__ __forceinline__ float fast_gelu(float x) {
  float s = x * 0.7071067811865475f;
  float ax = fabsf(s);
  float t = 1.0f / (1.0f + 0.3275911f * ax);
  float poly = t * (0.254829592f + t * (-0.284496736f + t * (1.421413741f +
               t * (-1.453152027f + t * 1.061405429f))));
  float e = __expf(-ax * ax);
  float r = 1.0f - poly * e;
  float erfv = copysignf(r, s);
  return 0.5f * x * (1.0f + erfv);
}

// ---------------------------------------------------------------- cast x -> fp16
__global__ void cast_f16_k(const float* __restrict__ in, u16* __restrict__ out, int n) {
  int i = (blockIdx.x * blockDim.x + threadIdx.x) * 4;
  if (i + 3 < n) {
    float4 f = *(const float4*)(in + i);
    u16x4 h;
    h.x = f2h_bits(f.x); h.y = f2h_bits(f.y);
    h.z = f2h_bits(f.z); h.w = f2h_bits(f.w);
    *(u16x4*)(out + i) = h;
  }
}

// -------------------- transpose W[K][N] -> Wt[N][K] fp16, 64x64 tile, u16x8 stores
__global__ void transpose_f16_k(const float* __restrict__ in, u16* __restrict__ out,
                                int K, int N) {
  __shared__ u16 tileT[64][72];   // [n_local][k_local], row 144B (16B-aligned)
  const int n0 = blockIdx.x * 64, k0 = blockIdx.y * 64;
  const int tid = threadIdx.x;    // 256
  const int kl = tid >> 4;        // 0..15
  const int nl4 = (tid & 15) * 4; // 0..60
  #pragma unroll
  for (int i = 0; i < 4; i++) {
    int k = kl + i * 16;
    float4 f = *(const float4*)(in + (size_t)(k0 + k) * N + n0 + nl4);
    tileT[nl4 + 0][k] = f2h_bits(f.x);
    tileT[nl4 + 1][k] = f2h_bits(f.y);
    tileT[nl4 + 2][k] = f2h_bits(f.z);
    tileT[nl4 + 3][k] = f2h_bits(f.w);
  }
  __syncthreads();
  const int nr = tid >> 3;         // 0..31
  const int ks = (tid & 7) * 8;    // 0..56
  #pragma unroll
  for (int p = 0; p < 2; p++) {
    int n = nr + p * 32;
    u16x8 v = *(const u16x8*)&tileT[n][ks];             // 16B LDS read
    *(u16x8*)(out + (size_t)(n0 + n) * K + k0 + ks) = v; // 16B global store
  }
}

// ---------------------------------------------------------------- QKV GEMM
// 128x128 tile, BK=64, 4 waves, fp16 MFMA, double-buffered LDS staging.
// q fp16 [B][H][N][D]; k fp16 [B][H][N][D]; v transposed fp16 [B][H][D][N].
__global__ __launch_bounds__(256, 2) void qkv_gemm_k(
    const u16* __restrict__ xf, const u16* __restrict__ Wqt,
    const u16* __restrict__ Wkt, const u16* __restrict__ Wvt,
    const float* __restrict__ bq, const float* __restrict__ bk, const float* __restrict__ bv,
    u16* __restrict__ qho, u16* __restrict__ ko, u16* __restrict__ vTo) {
  __shared__ __align__(16) u16 As[2][16 * 512];   // 2x16KB
  __shared__ __align__(16) u16 Bs[2][16 * 512];   // 2x16KB
  const int which = blockIdx.z;
  const u16* Wt = which == 0 ? Wqt : (which == 1 ? Wkt : Wvt);
  const float* bias = which == 0 ? bq : (which == 1 ? bk : bv);
  const int m0 = blockIdx.x * 128;
  const int n0 = blockIdx.y * 128;
  const int tid = threadIdx.x;
  const int w = tid >> 6, lane = tid & 63, l15 = lane & 15, quad = lane >> 4;
  const int mhalf = w >> 1, nhalf = w & 1;

  auto stage = [&](int s) {
    int kk = s * 64, buf = s & 1;
    #pragma unroll
    for (int i = 0; i < 8; i++) {
      int cb = w * 8 + i;
      if (cb < 16) {
        int ks = cb >> 3, mt = cb & 7;
        gll16(xf + (size_t)(m0 + mt * 16 + l15) * 512 + kk + ks * 32 + quad * 8,
              &As[buf][cb * 512]);
      } else {
        int bi = cb - 16, ks = bi >> 3, nt = bi & 7;
        gll16(Wt + (size_t)(n0 + nt * 16 + l15) * 512 + kk + ks * 32 + quad * 8,
              &Bs[buf][bi * 512]);
      }
    }
  };

  f32x4 acc[4][4];
  #pragma unroll
  for (int i = 0; i < 4; i++)
    #pragma unroll
    for (int j = 0; j < 4; j++) acc[i][j] = f32x4{0.f, 0.f, 0.f, 0.f};

  stage(0);
  __syncthreads();
  for (int s = 0; s < 8; s++) {
    if (s < 7) stage(s + 1);
    int buf = s & 1;
    #pragma unroll
    for (int ks = 0; ks < 2; ks++) {
      f16x8 a[4], b[4];
      #pragma unroll
      for (int mt = 0; mt < 4; mt++)
        a[mt] = *(const f16x8*)(&As[buf][(ks * 8 + mhalf * 4 + mt) * 512 + lane * 8]);
      #pragma unroll
      for (int nt = 0; nt < 4; nt++)
        b[nt] = *(const f16x8*)(&Bs[buf][(ks * 8 + nhalf * 4 + nt) * 512 + lane * 8]);
      #pragma unroll
      for (int mt = 0; mt < 4; mt++)
        #pragma unroll
        for (int nt = 0; nt < 4; nt++)
          acc[mt][nt] = __builtin_amdgcn_mfma_f32_16x16x32_f16(a[mt], b[nt], acc[mt][nt], 0, 0, 0);
    }
    __syncthreads();
  }
  #pragma unroll
  for (int nt = 0; nt < 4; nt++) {
    int col = n0 + (nhalf * 4 + nt) * 16 + l15;
    float bia = bias[col];
    int h = col >> 6, d = col & 63;
    #pragma unroll
    for (int mt = 0; mt < 4; mt++) {
      #pragma unroll
      for (int r = 0; r < 4; r++) {
        int t = m0 + (mhalf * 4 + mt) * 16 + quad * 4 + r;
        int b_ = t >> 10, n = t & 1023;
        float val = acc[mt][nt][r] + bia;
        size_t idx = (((size_t)(b_ * 8 + h) * 1024) + n) * 64 + d;
        if (which == 0)      qho[idx] = f2h_bits(val);
        else if (which == 1) ko[idx] = f2h_bits(val);
        else                 vTo[(((size_t)(b_ * 8 + h) * 64) + d) * 1024 + n] = f2h_bits(val);
      }
    }
  }
}

// ---------------------------------------------------------------- fused g-GEMM + q.g
// R10 = R6 compute structure + 3 blocks/CU. Block = 512 thr (8 waves) =
// 128 tok x head x j-QUARTER (8 chunks as 4 j-pairs). Per stage: As 16KB
// (x-tile) + Bs 32KB (256 cols) = 48KB LDS -> 3 blocks/CU (144KB).
// Single-buffered, 2 barriers/stage (R7/R8 showed dbuf/reg-stream lose).
// No Qs: q pairs are read from global at jp-start (8 stages of latency cover).
// Grid 1024 = head(8) x t0(32) x jq(4) -> 4 blocks/CU avg, 3 resident.
// qg partial per jq (stride TOK*EDIM); attn_k sums 4.
__global__ __launch_bounds__(512, 2) void qg_fused_k(
    const u16* __restrict__ xf, const u16* __restrict__ Wgt,
    const float* __restrict__ bg, const u16* __restrict__ qh,
    float* __restrict__ qgp) {
  __shared__ __align__(16) u16 As[16 * 512];   // 16KB: 128 tok x 64 K
  __shared__ __align__(16) u16 Bs[32 * 512];   // 32KB: 256 cols x 64 K
  const int bx = blockIdx.x;
  const int head = bx & 7;              // XCD-pinned per head
  const int t0 = ((bx >> 3) & 31) * 128;
  const int jq = bx >> 8;               // 0..3 j-quarter
  const int tid = threadIdx.x;
  const int w = tid >> 6, lane = tid & 63, l15 = lane & 15, quad = lane >> 4;
  const int mhalf = w >> 2;   // 0..1  (token half)
  const int ntA = w & 3;      // 0..3  (e-range /16)
  const int b_ = t0 >> 10, nseq0 = t0 & 1023;
  const u16* qbase = qh + (((size_t)(b_ * 8 + head) * 1024) + nseq0) * 64;

  f32x4 qg[4];
  #pragma unroll
  for (int i = 0; i < 4; i++) qg[i] = f32x4{0.f, 0.f, 0.f, 0.f};

  for (int jp = 0; jp < 4; jp++) {
    const int j0 = jq * 8 + jp * 2;               // pair (j0, j0+1)
    const int c0 = head * 4096 + j0 * 128;        // 256 contiguous cols
    const int d0 = 2 * j0;
    // preload q[row][d0..d0+3] from global (consumed after 8 stages)
    uint2 qq[4][4];
    #pragma unroll
    for (int mt = 0; mt < 4; mt++)
      #pragma unroll
      for (int r = 0; r < 4; r++) {
        int row = mhalf * 64 + mt * 16 + quad * 4 + r;
        qq[mt][r] = *(const uint2*)(qbase + (size_t)row * 64 + d0);
      }
    float bgv[4];
    #pragma unroll
    for (int z = 0; z < 4; z++) {
      int nt = (z >> 1) * 8 + (z & 1) * 4 + ntA;
      bgv[z] = bg[c0 + nt * 16 + l15];
    }

    f32x4 zacc[4][4];   // [mt][z]: z -> d = d0 + 2*(z>>1) + (z&1)
    #pragma unroll
    for (int i = 0; i < 4; i++)
      #pragma unroll
      for (int z = 0; z < 4; z++) zacc[i][z] = f32x4{0.f, 0.f, 0.f, 0.f};

    for (int kk = 0; kk < 8; kk++) {
      // 48 fragment blocks: As 16 (ks*8+mt) + Bs 32 (ks*16+nt), 6 per wave
      #pragma unroll
      for (int i = 0; i < 6; i++) {
        int cb = w * 6 + i;
        if (cb < 16) {
          int ks = cb >> 3, mt = cb & 7;
          gll16(xf + (size_t)(t0 + mt * 16 + l15) * 512 + kk * 64 + ks * 32 + quad * 8,
                As + cb * 512);
        } else {
          int bi = cb - 16, ks = bi >> 4, nt = bi & 15;
          gll16(Wgt + (size_t)(c0 + nt * 16 + l15) * 512 + kk * 64 + ks * 32 + quad * 8,
                Bs + bi * 512);
        }
      }
      __syncthreads();
      #pragma unroll
      for (int ks = 0; ks < 2; ks++) {
        f16x8 a[4];
        #pragma unroll
        for (int mt = 0; mt < 4; mt++)
          a[mt] = *(const f16x8*)(As + (ks * 8 + mhalf * 4 + mt) * 512 + lane * 8);
        #pragma unroll
        for (int z = 0; z < 4; z++) {
          int nt = (z >> 1) * 8 + (z & 1) * 4 + ntA;
          f16x8 b = *(const f16x8*)(Bs + (ks * 16 + nt) * 512 + lane * 8);
          #pragma unroll
          for (int mt = 0; mt < 4; mt++)
            zacc[mt][z] = __builtin_amdgcn_mfma_f32_16x16x32_f16(a[mt], b, zacc[mt][z], 0, 0, 0);
        }
      }
      __syncthreads();
    }
    // epilogue: bias + fast gelu + contract with q (d0..d0+3)
    #pragma unroll
    for (int mt = 0; mt < 4; mt++) {
      #pragma unroll
      for (int r = 0; r < 4; r++) {
        float q0 = h2f((u16)(qq[mt][r].x & 0xffffu));
        float q1 = h2f((u16)(qq[mt][r].x >> 16));
        float q2 = h2f((u16)(qq[mt][r].y & 0xffffu));
        float q3 = h2f((u16)(qq[mt][r].y >> 16));
        qg[mt][r] += q0 * fast_gelu(zacc[mt][0][r] + bgv[0]) +
                     q1 * fast_gelu(zacc[mt][1][r] + bgv[1]) +
                     q2 * fast_gelu(zacc[mt][2][r] + bgv[2]) +
                     q3 * fast_gelu(zacc[mt][3][r] + bgv[3]);
      }
    }
  }
  float* qout = qgp + (size_t)jq * TOK * EDIM;   // partial per j-quarter
  const int eb = ntA * 16;
  #pragma unroll
  for (int mt = 0; mt < 4; mt++) {
    #pragma unroll
    for (int r = 0; r < 4; r++) {
      int t = t0 + mhalf * 64 + mt * 16 + quad * 4 + r;
      int bb = t >> 10, n = t & 1023;
      qout[(((size_t)(bb * 8 + head) * 1024) + n) * 64 + eb + l15] = qg[mt][r];
    }
  }
}

// ---------------------------------------------------------------- flash attention
// Block = (b,h,qtile64), 4 waves x 16 q-rows. qg = sum of 4 jq-partials
// (fp32->fp16), S = qg@k^T fp16 MFMA, online softmax, P->LDS, O += P@V.
__global__ __launch_bounds__(256, 2) void attn_k(
    const float* __restrict__ qgp, const u16* __restrict__ kb,
    const u16* __restrict__ vTb, float* __restrict__ out) {
  __shared__ __align__(16) u16 Ks[8 * 512];
  __shared__ __align__(16) u16 Vs[8 * 512];
  __shared__ __align__(16) f16 Ps[4][16 * 72];    // per-wave P, row stride 72
  const int idx = blockIdx.x;
  const int bh = idx & 31;   // b*8+h -> XCD = bh%8
  const int qt = idx >> 5;
  const int b_ = bh >> 3, h = bh & 7;
  const int tid = threadIdx.x;
  const int w = tid >> 6, lane = tid & 63, l15 = lane & 15, quad = lane >> 4;

  const size_t S = (size_t)TOK * EDIM;           // partial stride
  const float* qgB = qgp + (size_t)bh * 1024 * 64;
  const u16* kB  = kb  + (size_t)bh * 1024 * 64;
  const u16* vB  = vTb + (size_t)bh * 64 * 1024;

  f16x8 aq[2];
  #pragma unroll
  for (int ks = 0; ks < 2; ks++) {
    size_t off = (size_t)(qt * 64 + w * 16 + l15) * 64 + ks * 32 + quad * 8;
    f16x8 v;
    #pragma unroll
    for (int e = 0; e < 8; e++)
      v[e] = (f16)(qgB[off + e] + qgB[S + off + e] + qgB[2 * S + off + e] + qgB[3 * S + off + e]);
    aq[ks] = v;
  }

  f32x4 o[4];
  #pragma unroll
  for (int i = 0; i < 4; i++) o[i] = f32x4{0.f, 0.f, 0.f, 0.f};
  float m_old[4], l_old[4];
  #pragma unroll
  for (int r = 0; r < 4; r++) { m_old[r] = -1e30f; l_old[r] = 0.f; }

  for (int kt = 0; kt < 16; kt++) {
    #pragma unroll
    for (int i = 0; i < 2; i++) {
      int cb = w * 2 + i;
      int ks = cb >> 2, nt = cb & 3;
      gll16(kB + (size_t)(kt * 64 + nt * 16 + l15) * 64 + ks * 32 + quad * 8, Ks + cb * 512);
      gll16(vB + (size_t)(nt * 16 + l15) * 1024 + kt * 64 + ks * 32 + quad * 8, Vs + cb * 512);
    }
    __syncthreads();
    f32x4 s[4];
    #pragma unroll
    for (int nt = 0; nt < 4; nt++) s[nt] = f32x4{0.f, 0.f, 0.f, 0.f};
    #pragma unroll
    for (int ks = 0; ks < 2; ks++)
      #pragma unroll
      for (int nt = 0; nt < 4; nt++) {
        f16x8 kf = *(const f16x8*)(Ks + (ks * 4 + nt) * 512 + lane * 8);
        s[nt] = __builtin_amdgcn_mfma_f32_16x16x32_f16(aq[ks], kf, s[nt], 0, 0, 0);
      }
    float rmax[4];
    #pragma unroll
    for (int r = 0; r < 4; r++)
      rmax[r] = fmaxf(fmaxf(s[0][r], s[1][r]), fmaxf(s[2][r], s[3][r]));
    #pragma unroll
    for (int off = 1; off < 16; off <<= 1)
      #pragma unroll
      for (int r = 0; r < 4; r++)
        rmax[r] = fmaxf(rmax[r], __shfl_xor(rmax[r], off));
    float alpha[4], rsum[4];
    #pragma unroll
    for (int r = 0; r < 4; r++) {
      float mn = fmaxf(m_old[r], rmax[r]);
      alpha[r] = __expf(m_old[r] - mn);
      m_old[r] = mn;
      rsum[r] = 0.f;
    }
    #pragma unroll
    for (int nt = 0; nt < 4; nt++)
      #pragma unroll
      for (int r = 0; r < 4; r++) {
        float p = __expf(s[nt][r] - m_old[r]);
        rsum[r] += p;
        Ps[w][(quad * 4 + r) * 72 + nt * 16 + l15] = (f16)p;
      }
    #pragma unroll
    for (int off = 1; off < 16; off <<= 1)
      #pragma unroll
      for (int r = 0; r < 4; r++)
        rsum[r] += __shfl_xor(rsum[r], off);
    #pragma unroll
    for (int r = 0; r < 4; r++) l_old[r] = l_old[r] * alpha[r] + rsum[r];
    #pragma unroll
    for (int nt = 0; nt < 4; nt++)
      #pragma unroll
      for (int r = 0; r < 4; r++) o[nt][r] *= alpha[r];
    #pragma unroll
    for (int ks = 0; ks < 2; ks++) {
      f16x8 pa = *(const f16x8*)(&Ps[w][l15 * 72 + ks * 32 + quad * 8]);
      #pragma unroll
      for (int nt = 0; nt < 4; nt++) {
        f16x8 vf = *(const f16x8*)(Vs + (ks * 4 + nt) * 512 + lane * 8);
        o[nt] = __builtin_amdgcn_mfma_f32_16x16x32_f16(pa, vf, o[nt], 0, 0, 0);
      }
    }
    __syncthreads();
  }
  #pragma unroll
  for (int r = 0; r < 4; r++) {
    float inv = 1.f / l_old[r];
    int n = qt * 64 + w * 16 + quad * 4 + r;
    #pragma unroll
    for (int nt = 0; nt < 4; nt++)
      out[((size_t)(b_ * 1024 + n)) * 512 + h * 64 + nt * 16 + l15] = o[nt][r] * inv;
  }
}

// ----------------------------------------------------------------------- host
extern "C" void kernel_launch(void* const* d_in, const int* in_sizes, int n_in,
                              void* d_out, int out_size, void* d_ws, size_t ws_size,
                              hipStream_t stream) {
  const float* x  = (const float*)d_in[0];
  const float* Wq = (const float*)d_in[1];
  const float* bq = (const float*)d_in[2];
  const float* Wk = (const float*)d_in[3];
  const float* bk = (const float*)d_in[4];
  const float* Wv = (const float*)d_in[5];
  const float* bv = (const float*)d_in[6];
  const float* Wg = (const float*)d_in[7];
  const float* bg = (const float*)d_in[8];
  float* out = (float*)d_out;

  const size_t NX = (size_t)TOK * EDIM;        // 2M elems
  const size_t NWG = (size_t)GCOLS * EDIM;     // 16.8M elems
  const size_t NW = (size_t)EDIM * EDIM;       // 256K elems

  char* p = (char*)d_ws;
  u16* xf  = (u16*)p; p += NX * 2;             // x fp16
  u16* Wgt = (u16*)p; p += NWG * 2;            // Wg^T fp16 (33.5 MB)
  u16* Wqt = (u16*)p; p += NW * 2;
  u16* Wkt = (u16*)p; p += NW * 2;
  u16* Wvt = (u16*)p; p += NW * 2;
  u16* qh  = (u16*)p; p += NX * 2;             // q fp16 [B][H][N][D]
  u16* kf  = (u16*)p; p += NX * 2;             // k fp16
  u16* vT  = (u16*)p; p += NX * 2;             // v^T fp16
  float* qgp = (float*)p; p += NX * 4 * 4;     // qg fp32 partials [4 jq][B][H][N][D]

  hipLaunchKernelGGL(cast_f16_k, dim3(NX / 1024), dim3(256), 0, stream,
                     x, xf, (int)NX);
  hipLaunchKernelGGL(transpose_f16_k, dim3(EDIM / 64, EDIM / 64), dim3(256), 0, stream,
                     Wq, Wqt, EDIM, EDIM);
  hipLaunchKernelGGL(transpose_f16_k, dim3(EDIM / 64, EDIM / 64), dim3(256), 0, stream,
                     Wk, Wkt, EDIM, EDIM);
  hipLaunchKernelGGL(transpose_f16_k, dim3(EDIM / 64, EDIM / 64), dim3(256), 0, stream,
                     Wv, Wvt, EDIM, EDIM);
  hipLaunchKernelGGL(transpose_f16_k, dim3(GCOLS / 64, EDIM / 64), dim3(256), 0, stream,
                     Wg, Wgt, EDIM, GCOLS);
  hipLaunchKernelGGL(qkv_gemm_k, dim3(TOK / 128, EDIM / 128, 3), dim3(256), 0, stream,
                     xf, Wqt, Wkt, Wvt, bq, bk, bv, qh, kf, vT);
  hipLaunchKernelGGL(qg_fused_k, dim3(1024), dim3(512), 0, stream,
                     xf, Wgt, bg, qh, qgp);
  hipLaunchKernelGGL(attn_k, dim3(512), dim3(256), 0, stream,
                     qgp, kf, vT, out);
}